// Round 6
// baseline (327.219 us; speedup 1.0000x reference)
//
#include <hip/hip_runtime.h>

// Otsu-split loss. Round-6: force memory-level parallelism in k_main.
// R5 evidence: VGPR_Count=32 -> compiler sank the "prefetched" loads back to
// their uses (a float4+int4 pair alone is 8 VGPRs); each wave held only ~4KB
// in flight and stalled on vmcnt most of each ~900cy latency window.
// Fix: 512-thread blocks, __launch_bounds__(512,4) (VGPR cap 128), 8
// independent dwordx4 loads per iteration (8KB/wave in flight), slim PROC.
//
//   f(i) = T2 - S(i)^2/i - (T-S(i))^2/(K-i)   (s2-prefix cancels)
// Bracket [t_lo, t_lo+0.125) from 1/64 subsample; 32 fine bins, width 1/256,
// snapped to the 1/256 grid (absmax 0.0 in rounds 1-5 on this grid).

#define SBINS 1024          // subsample bins over [-4,4), width 1/128
#define FBINS 32            // fine bins, width 1/256 -> bracket width 1/8
#define MAIN_THREADS 512
#define MAIN_NW (MAIN_THREADS / 64)   // 8 waves
#define SAMP_THREADS 1024
#define PICK_THREADS 256
#define FIN_THREADS 1024

// ---------------- stage 1: subsample histogram (per-block, plain stores) ----
__global__ __launch_bounds__(SAMP_THREADS)
void k_sample(const float4* __restrict__ x4, const int4* __restrict__ m4,
              long n4, unsigned long long* __restrict__ sh, int sb) {
  __shared__ unsigned long long h[SBINS];  // 8 KiB
  for (int b = threadIdx.x; b < SBINS; b += SAMP_THREADS) h[b] = 0ull;
  __syncthreads();

  int gw = (int)((blockIdx.x * SAMP_THREADS + threadIdx.x) >> 6);
  int nwaves = sb * (SAMP_THREADS / 64);
  int lane = threadIdx.x & 63;
  long spacing = n4 / 2048; if (spacing < 64) spacing = 64;

#define SPROC(v_, m_)                                                  \
  if (m_) {                                                            \
    float v = (v_);                                                    \
    int b = (int)fmaf(v, 128.0f, 512.0f);                              \
    b = min(max(b, 0), SBINS - 1);                                     \
    unsigned q = __float2uint_rn(fmaf(v, 1048576.0f, 16777216.0f));    \
    atomicAdd(&h[b], (1ull << 42) + (unsigned long long)q);            \
  }

  for (int c = gw; c < 2048; c += nwaves) {
    long idx = (long)c * spacing + lane;
    if (idx < n4) {
      float4 xv = x4[idx];
      int4 mv = m4[idx];
      SPROC(xv.x, mv.x) SPROC(xv.y, mv.y) SPROC(xv.z, mv.z) SPROC(xv.w, mv.w)
    }
  }
#undef SPROC

  __syncthreads();
  for (int b = threadIdx.x; b < SBINS; b += SAMP_THREADS)
    sh[(long)blockIdx.x * SBINS + b] = h[b];   // plain coalesced store
}

// ---------------- stage 2: reduce sample hists, pick bracket ----------------
__global__ __launch_bounds__(PICK_THREADS)
void k_pick(const unsigned long long* __restrict__ sh, int sb,
            float* __restrict__ t_lo_out) {
  __shared__ unsigned long long sC[PICK_THREADS], sS[PICK_THREADS];
  __shared__ double rf[PICK_THREADS];
  __shared__ int rb[PICK_THREADS];
  int t = threadIdx.x;

  unsigned long long c[4], q[4], cc = 0, qq = 0;
  for (int j = 0; j < 4; j++) {
    int bin = t * 4 + j;
    unsigned long long hv = 0ull;
    for (int r = 0; r < sb; r++) hv += sh[(long)r * SBINS + bin];
    c[j] = hv >> 42; q[j] = hv & ((1ull << 42) - 1ull);
    cc += c[j]; qq += q[j];
  }
  sC[t] = cc; sS[t] = qq;
  __syncthreads();
  for (int off = 1; off < PICK_THREADS; off <<= 1) {
    unsigned long long ac = (t >= off) ? sC[t - off] : 0ull;
    unsigned long long as = (t >= off) ? sS[t - off] : 0ull;
    __syncthreads();
    sC[t] += ac; sS[t] += as;
    __syncthreads();
  }
  unsigned long long K = sC[PICK_THREADS - 1], Q = sS[PICK_THREADS - 1];
  double Tp = (double)Q * 9.5367431640625e-07 - 16.0 * (double)K;

  unsigned long long Ci = sC[t] - cc, Qi = sS[t] - qq;
  double bestf = 1.0e300; int bestb = -1;
  for (int j = 0; j < 4; j++) {
    Ci += c[j]; Qi += q[j];
    if (Ci >= 1ull && Ci < K) {
      double di = (double)Ci;
      double S = (double)Qi * 9.5367431640625e-07 - 16.0 * di;
      double d2 = Tp - S;
      double f = -S * S / di - d2 * d2 / ((double)K - di);
      if (f < bestf) { bestf = f; bestb = t * 4 + j; }
    }
  }
  rf[t] = bestf; rb[t] = bestb;
  __syncthreads();
  for (int off = PICK_THREADS / 2; off > 0; off >>= 1) {
    if (t < off && rf[t + off] < rf[t]) { rf[t] = rf[t + off]; rb[t] = rb[t + off]; }
    __syncthreads();
  }
  if (t == 0) {
    float t_lo = -0.0625f;
    if (rb[0] >= 0 && K >= 2ull) {
      float that = -4.0f + (float)(rb[0] + 1) * 0.0078125f;  // right edge of bin
      // snap to 1/256 grid, center the 32-bin bracket (16 bins each side)
      t_lo = (rintf(that * 256.0f) - 16.0f) * 0.00390625f;
    }
    *t_lo_out = t_lo;
  }
}

// ---------------- stage 3: full-data streaming pass ----------------
__global__ __launch_bounds__(MAIN_THREADS, 4)   // VGPR cap 128: room for 8 in-flight loads
void k_main(const float4* __restrict__ x4, const int4* __restrict__ m4, long n4,
            const float* __restrict__ xs, const int* __restrict__ ms, long n,
            const float* __restrict__ t_lo_p,
            double* __restrict__ Tb, double* __restrict__ T2b,
            double* __restrict__ Sbb, unsigned* __restrict__ Kb,
            unsigned* __restrict__ Cbb, unsigned long long* __restrict__ mh,
            int nblk) {
  __shared__ unsigned long long wh[MAIN_NW][FBINS];  // 2 KiB
  __shared__ float bT[MAIN_NW], bT2[MAIN_NW], bSb[MAIN_NW];
  __shared__ unsigned bK[MAIN_NW], bCb[MAIN_NW];

  int wave = threadIdx.x >> 6, lane = threadIdx.x & 63;
  unsigned long long* h = wh[wave];
  if (threadIdx.x < MAIN_NW * FBINS)
    ((unsigned long long*)wh)[threadIdx.x] = 0ull;
  __syncthreads();

  float t_lo = *t_lo_p;
  unsigned K = 0, Cb = 0;
  float T = 0.0f, T2 = 0.0f, Sb = 0.0f;

#define PROC(v_, mi_)                                                      \
  {                                                                        \
    int mi = (mi_);                                                        \
    float v = (v_);                                                        \
    float fm = (float)mi;                                                  \
    float vm = v * fm;                                                     \
    K += (unsigned)mi; T += vm; T2 = fmaf(vm, vm, T2);                     \
    float rel = v - t_lo;                                                  \
    bool below = (mi != 0) & (rel < 0.0f);                                 \
    Cb += below; Sb += below ? v : 0.0f;                                   \
    int bb = (int)(rel * 256.0f);                                          \
    if ((mi != 0) & (rel >= 0.0f) & (bb < FBINS)) {                        \
      unsigned q = __float2uint_rn(fmaf(v, 1048576.0f, 16777216.0f));      \
      atomicAdd(&h[bb], (1ull << 42) + (unsigned long long)q);             \
    }                                                                      \
  }
#define PROC4(xv, mv) { PROC(xv.x, mv.x) PROC(xv.y, mv.y) PROC(xv.z, mv.z) PROC(xv.w, mv.w) }

  long tid0 = (long)blockIdx.x * MAIN_THREADS + threadIdx.x;
  long s = (long)nblk * MAIN_THREADS;
  long step = 4 * s;
  long nfull = (n4 - tid0 + step - 1) >= 0 ? (n4 > tid0 ? 0 : 0) : 0;  // (computed below)
  // clean loop: j such that j+3s < n4
  long j = tid0;
  for (; j + 3 * s < n4; j += step) {
    // issue 8 independent loads; compiler keeps them in flight (128-VGPR cap)
    float4 xa = x4[j];         int4 ma = m4[j];
    float4 xb = x4[j + s];     int4 mb2 = m4[j + s];
    float4 xc = x4[j + 2 * s]; int4 mc = m4[j + 2 * s];
    float4 xd = x4[j + 3 * s]; int4 md = m4[j + 3 * s];
    PROC4(xa, ma) PROC4(xb, mb2) PROC4(xc, mc) PROC4(xd, md)
  }
  for (; j < n4; j += s) {  // tail batches
    float4 xa = x4[j]; int4 ma = m4[j];
    PROC4(xa, ma)
  }
  if (blockIdx.x == 0 && threadIdx.x == 0) {  // element tail (n not multiple of 4)
    for (long i = n4 * 4; i < n; i++) { PROC(xs[i], ms[i]) }
  }
#undef PROC4
#undef PROC

  // wave shuffle reduce -> block reduce -> PLAIN per-block stores (no atomics)
  for (int off = 32; off > 0; off >>= 1) {
    K += __shfl_down(K, off);
    Cb += __shfl_down(Cb, off);
    T += __shfl_down(T, off);
    T2 += __shfl_down(T2, off);
    Sb += __shfl_down(Sb, off);
  }
  if (lane == 0) { bK[wave] = K; bCb[wave] = Cb; bT[wave] = T; bT2[wave] = T2; bSb[wave] = Sb; }
  __syncthreads();
  if (threadIdx.x == 0) {
    unsigned k = 0, cb = 0; double t = 0.0, t2 = 0.0, sb_ = 0.0;
    for (int w = 0; w < MAIN_NW; w++) {
      k += bK[w]; cb += bCb[w]; t += (double)bT[w]; t2 += (double)bT2[w]; sb_ += (double)bSb[w];
    }
    Kb[blockIdx.x] = k; Cbb[blockIdx.x] = cb;
    Tb[blockIdx.x] = t; T2b[blockIdx.x] = t2; Sbb[blockIdx.x] = sb_;
  }
  if (threadIdx.x < FBINS) {
    int b = threadIdx.x;
    unsigned long long tot = 0ull;
    for (int w = 0; w < MAIN_NW; w++) tot += wh[w][b];
    mh[(long)blockIdx.x * FBINS + b] = tot;   // plain coalesced store
  }
}

// ---------------- stage 4: reduce partials, argmin, output ----------------
__global__ __launch_bounds__(FIN_THREADS)
void k_fin(const double* __restrict__ Tb, const double* __restrict__ T2b,
           const double* __restrict__ Sbb, const unsigned* __restrict__ Kb,
           const unsigned* __restrict__ Cbb,
           const unsigned long long* __restrict__ mh, int nblk,
           float* __restrict__ out) {
  __shared__ double lT[16], lT2[16], lSb[16];
  __shared__ unsigned long long lK[16], lCb[16];
  __shared__ unsigned long long pc[32][FBINS], pq[32][FBINS];  // 16 KiB
  __shared__ double gT, gT2, gSb;
  __shared__ unsigned long long gK, gCb;

  int t = threadIdx.x;
  int wave = t >> 6, lane = t & 63;

  // ---- scalar totals ----
  double T = 0.0, T2 = 0.0, Sb = 0.0;
  unsigned long long K = 0, Cb = 0;
  for (int i = t; i < nblk; i += FIN_THREADS) {
    T += Tb[i]; T2 += T2b[i]; Sb += Sbb[i];
    K += Kb[i]; Cb += Cbb[i];
  }
  for (int off = 32; off > 0; off >>= 1) {
    T += __shfl_down(T, off); T2 += __shfl_down(T2, off); Sb += __shfl_down(Sb, off);
    K += __shfl_down(K, off); Cb += __shfl_down(Cb, off);
  }
  if (lane == 0) { lT[wave] = T; lT2[wave] = T2; lSb[wave] = Sb; lK[wave] = K; lCb[wave] = Cb; }

  // ---- hist totals: thread -> (chunk = t>>5, bin = t&31), chunks stride blocks
  {
    int chunk = t >> 5, bin = t & 31;
    if (chunk < 32) {
      unsigned long long hc = 0, hq = 0;
      for (int i = chunk; i < nblk; i += 32) {
        unsigned long long v = mh[(long)i * FBINS + bin];
        hc += v >> 42; hq += v & ((1ull << 42) - 1ull);
      }
      pc[chunk][bin] = hc; pq[chunk][bin] = hq;
    }
  }
  __syncthreads();

  if (t == 0) {
    double a = 0, b = 0, c = 0; unsigned long long k = 0, cb = 0;
    for (int w = 0; w < 16; w++) { a += lT[w]; b += lT2[w]; c += lSb[w]; k += lK[w]; cb += lCb[w]; }
    gT = a; gT2 = b; gSb = c; gK = k; gCb = cb;
  }
  __syncthreads();

  if (t < 64) {  // wave 0: bins in lanes 0..31, lanes 32..63 ride along
    bool valid = lane < FBINS;
    unsigned long long c = 0, q = 0;
    if (valid) for (int w = 0; w < 32; w++) { c += pc[w][lane]; q += pq[w][lane]; }
    // inclusive scan over 32 bins (full-wave shuffles; upper lanes junk)
    for (int off = 1; off < FBINS; off <<= 1) {
      unsigned long long cc = __shfl_up(c, off);
      unsigned long long qq = __shfl_up(q, off);
      if (lane >= off && valid) { c += cc; q += qq; }
    }
    double kd = (double)gK;
    double T_ = gT, T2_ = gT2;
    double Ccand = 0.0, Scand = 0.0, f = 1.0e300;
    if (valid) {
      Ccand = (double)gCb + (double)c;
      Scand = gSb + ((double)q * 9.5367431640625e-07 - 16.0 * (double)c);
      if (Ccand >= 1.0 && Ccand < kd) {
        double d2 = T_ - Scand;
        f = T2_ - Scand * Scand / Ccand - d2 * d2 / (kd - Ccand);
      } else {
        f = 1.0e300;
      }
      if (lane == 0) {  // extra candidate: split exactly at t_lo (empty prefix)
        double C0 = (double)gCb, S0 = gSb;
        if (C0 >= 1.0 && C0 < kd) {
          double d2 = T_ - S0;
          double f0 = T2_ - S0 * S0 / C0 - d2 * d2 / (kd - C0);
          if (f0 < f) { f = f0; Ccand = C0; Scand = S0; }
        }
      }
    }
    for (int off = 32; off > 0; off >>= 1) {
      double of = __shfl_down(f, off);
      double oS = __shfl_down(Scand, off);
      double oC = __shfl_down(Ccand, off);
      if (of < f) { f = of; Scand = oS; Ccand = oC; }
    }
    if (lane == 0) {
      double result = 0.0;
      if (gK >= 2ull && f < 1.0e300 && Ccand >= 1.0) {
        double var_tot = (T2_ - T_ * T_ / kd) / kd;
        double reg = f / var_tot / kd;
        result = Scand / Ccand + 0.5 * reg;
      }
      out[0] = (float)result;
    }
  }
}

extern "C" void kernel_launch(void* const* d_in, const int* in_sizes, int n_in,
                              void* d_out, int out_size, void* d_ws, size_t ws_size,
                              hipStream_t stream) {
  const float* x = (const float*)d_in[0];
  const int* m = (const int*)d_in[1];
  long n = (long)in_sizes[0];
  long n4 = n >> 2;

  // choose block counts to fit ws_size (deterministic per capture)
  int mb = 1024, sb = 32;
  size_t need;
  for (;;) {
    need = 64 + (size_t)mb * (3 * sizeof(double) + 2 * sizeof(unsigned))
         + (size_t)mb * FBINS * 8 + (size_t)sb * SBINS * 8 + 64;
    if (need <= ws_size || (mb <= 64 && sb <= 8)) break;
    if (mb > 64) mb >>= 1;
    else sb >>= 1;
  }

  char* p = (char*)d_ws;
  float* t_lo = (float*)p;
  double* Tb = (double*)(p + 64);
  double* T2b = Tb + mb;
  double* Sbb = T2b + mb;
  unsigned long long* mh = (unsigned long long*)(Sbb + mb);
  unsigned* Kb = (unsigned*)(mh + (size_t)mb * FBINS);
  unsigned* Cbb = Kb + mb;
  unsigned long long* sh =
      (unsigned long long*)(((uintptr_t)(Cbb + mb) + 7) & ~(uintptr_t)7);

  k_sample<<<sb, SAMP_THREADS, 0, stream>>>((const float4*)x, (const int4*)m, n4, sh, sb);
  k_pick<<<1, PICK_THREADS, 0, stream>>>(sh, sb, t_lo);
  k_main<<<mb, MAIN_THREADS, 0, stream>>>((const float4*)x, (const int4*)m, n4,
                                          x, m, n, t_lo, Tb, T2b, Sbb, Kb, Cbb, mh, mb);
  k_fin<<<1, FIN_THREADS, 0, stream>>>(Tb, T2b, Sbb, Kb, Cbb, mh, mb, (float*)d_out);
}

// Round 8
// 287.038 us; speedup vs baseline: 1.1400x; 1.1400x over previous
//
#include <hip/hip_runtime.h>

// Otsu-split loss. Round-8 = round-7 theory with the compile fix:
// __builtin_nontemporal_load needs native clang ext_vector types, not HIP's
// float4/int4 structs.
//
// Rounds 4-6: three different k_main shapes all plateau at 102-110us
// (2.6 TB/s effective) with FETCH_SIZE == exactly HALF the 268MB footprint.
// Working set (268MB) is just over the 256MB LLC -> ~50% interleaved L3
// hits/misses; the hole-punched HBM stream + fabric contention caps both
// halves at ~1.3 TB/s. Fix: nt loads bypass LLC retention -> clean HBM stream.
//
//   f(i) = T2 - S(i)^2/i - (T-S(i))^2/(K-i)   (s2-prefix cancels)
// Bracket [t_lo, t_lo+0.125) from 1/64 subsample; 32 fine bins, width 1/256,
// snapped to the 1/256 grid (absmax 0.0 in rounds 1-6 on this grid).

#define SBINS 1024          // subsample bins over [-4,4), width 1/128
#define FBINS 32            // fine bins, width 1/256 -> bracket width 1/8
#define MAIN_THREADS 1024
#define MAIN_NW (MAIN_THREADS / 64)   // 16 waves
#define SAMP_THREADS 1024
#define PICK_THREADS 256
#define FIN_THREADS 1024

typedef float vfloat4 __attribute__((ext_vector_type(4)));
typedef int vint4 __attribute__((ext_vector_type(4)));

__device__ __forceinline__ vfloat4 nt_load_f4(const float4* p) {
  return __builtin_nontemporal_load((const vfloat4*)p);
}
__device__ __forceinline__ vint4 nt_load_i4(const int4* p) {
  return __builtin_nontemporal_load((const vint4*)p);
}

// ---------------- stage 1: subsample histogram (per-block, plain stores) ----
__global__ __launch_bounds__(SAMP_THREADS)
void k_sample(const float4* __restrict__ x4, const int4* __restrict__ m4,
              long n4, unsigned long long* __restrict__ sh, int sb) {
  __shared__ unsigned long long h[SBINS];  // 8 KiB
  for (int b = threadIdx.x; b < SBINS; b += SAMP_THREADS) h[b] = 0ull;
  __syncthreads();

  int gw = (int)((blockIdx.x * SAMP_THREADS + threadIdx.x) >> 6);
  int nwaves = sb * (SAMP_THREADS / 64);
  int lane = threadIdx.x & 63;
  long spacing = n4 / 2048; if (spacing < 64) spacing = 64;

#define SPROC(v_, m_)                                                  \
  if (m_) {                                                            \
    float v = (v_);                                                    \
    int b = (int)fmaf(v, 128.0f, 512.0f);                              \
    b = min(max(b, 0), SBINS - 1);                                     \
    unsigned q = __float2uint_rn(fmaf(v, 1048576.0f, 16777216.0f));    \
    atomicAdd(&h[b], (1ull << 42) + (unsigned long long)q);            \
  }

  for (int c = gw; c < 2048; c += nwaves) {
    long idx = (long)c * spacing + lane;
    if (idx < n4) {
      float4 xv = x4[idx];
      int4 mv = m4[idx];
      SPROC(xv.x, mv.x) SPROC(xv.y, mv.y) SPROC(xv.z, mv.z) SPROC(xv.w, mv.w)
    }
  }
#undef SPROC

  __syncthreads();
  for (int b = threadIdx.x; b < SBINS; b += SAMP_THREADS)
    sh[(long)blockIdx.x * SBINS + b] = h[b];   // plain coalesced store
}

// ---------------- stage 2: reduce sample hists, pick bracket ----------------
__global__ __launch_bounds__(PICK_THREADS)
void k_pick(const unsigned long long* __restrict__ sh, int sb,
            float* __restrict__ t_lo_out) {
  __shared__ unsigned long long sC[PICK_THREADS], sS[PICK_THREADS];
  __shared__ double rf[PICK_THREADS];
  __shared__ int rb[PICK_THREADS];
  int t = threadIdx.x;

  unsigned long long c[4], q[4], cc = 0, qq = 0;
  for (int j = 0; j < 4; j++) {
    int bin = t * 4 + j;
    unsigned long long hv = 0ull;
    for (int r = 0; r < sb; r++) hv += sh[(long)r * SBINS + bin];
    c[j] = hv >> 42; q[j] = hv & ((1ull << 42) - 1ull);
    cc += c[j]; qq += q[j];
  }
  sC[t] = cc; sS[t] = qq;
  __syncthreads();
  for (int off = 1; off < PICK_THREADS; off <<= 1) {
    unsigned long long ac = (t >= off) ? sC[t - off] : 0ull;
    unsigned long long as = (t >= off) ? sS[t - off] : 0ull;
    __syncthreads();
    sC[t] += ac; sS[t] += as;
    __syncthreads();
  }
  unsigned long long K = sC[PICK_THREADS - 1], Q = sS[PICK_THREADS - 1];
  double Tp = (double)Q * 9.5367431640625e-07 - 16.0 * (double)K;

  unsigned long long Ci = sC[t] - cc, Qi = sS[t] - qq;
  double bestf = 1.0e300; int bestb = -1;
  for (int j = 0; j < 4; j++) {
    Ci += c[j]; Qi += q[j];
    if (Ci >= 1ull && Ci < K) {
      double di = (double)Ci;
      double S = (double)Qi * 9.5367431640625e-07 - 16.0 * di;
      double d2 = Tp - S;
      double f = -S * S / di - d2 * d2 / ((double)K - di);
      if (f < bestf) { bestf = f; bestb = t * 4 + j; }
    }
  }
  rf[t] = bestf; rb[t] = bestb;
  __syncthreads();
  for (int off = PICK_THREADS / 2; off > 0; off >>= 1) {
    if (t < off && rf[t + off] < rf[t]) { rf[t] = rf[t + off]; rb[t] = rb[t + off]; }
    __syncthreads();
  }
  if (t == 0) {
    float t_lo = -0.0625f;
    if (rb[0] >= 0 && K >= 2ull) {
      float that = -4.0f + (float)(rb[0] + 1) * 0.0078125f;  // right edge of bin
      // snap to 1/256 grid, center the 32-bin bracket (16 bins each side)
      t_lo = (rintf(that * 256.0f) - 16.0f) * 0.00390625f;
    }
    *t_lo_out = t_lo;
  }
}

// ---------------- stage 3: full-data streaming pass ----------------
__global__ __launch_bounds__(MAIN_THREADS, 8)
void k_main(const float4* __restrict__ x4, const int4* __restrict__ m4, long n4,
            const float* __restrict__ xs, const int* __restrict__ ms, long n,
            const float* __restrict__ t_lo_p,
            double* __restrict__ Tb, double* __restrict__ T2b,
            double* __restrict__ Sbb, unsigned* __restrict__ Kb,
            unsigned* __restrict__ Cbb, unsigned long long* __restrict__ mh,
            int nblk) {
  __shared__ unsigned long long wh[MAIN_NW][FBINS];  // 4 KiB
  __shared__ float bT[MAIN_NW], bT2[MAIN_NW], bSb[MAIN_NW];
  __shared__ unsigned bK[MAIN_NW], bCb[MAIN_NW];

  int wave = threadIdx.x >> 6, lane = threadIdx.x & 63;
  unsigned long long* h = wh[wave];
  if (threadIdx.x < MAIN_NW * FBINS)
    ((unsigned long long*)wh)[threadIdx.x] = 0ull;
  __syncthreads();

  float t_lo = *t_lo_p;
  unsigned K = 0, Cb = 0;
  float T = 0.0f, T2 = 0.0f, Sb = 0.0f;

#define PROC(v_, m_)                                                       \
  {                                                                        \
    bool mm = (m_) != 0;                                                   \
    float v = (v_);                                                        \
    float vm = mm ? v : 0.0f;                                              \
    K += mm; T += vm; T2 = fmaf(vm, vm, T2);                               \
    bool below = mm && (v < t_lo);                                         \
    Cb += below; Sb += below ? v : 0.0f;                                   \
    float rel = v - t_lo;                                                  \
    if (mm && rel >= 0.0f && rel < 0.125f) {                               \
      int b = (int)(rel * 256.0f);                                         \
      unsigned q = __float2uint_rn(fmaf(v, 1048576.0f, 16777216.0f));      \
      atomicAdd(&h[b], (1ull << 42) + (unsigned long long)q);              \
    }                                                                      \
  }
#define PROC4(xv, mv) { PROC(xv.x, mv.x) PROC(xv.y, mv.y) PROC(xv.z, mv.z) PROC(xv.w, mv.w) }

  long tid = (long)blockIdx.x * MAIN_THREADS + threadIdx.x;
  long stride = (long)nblk * MAIN_THREADS;
  if (tid < n4) {
    vfloat4 xv = nt_load_f4(x4 + tid); vint4 mv = nt_load_i4(m4 + tid);
    for (long j = tid + stride; j < n4; j += stride) {
      vfloat4 xn = nt_load_f4(x4 + j);   // prefetch next iteration
      vint4 mn = nt_load_i4(m4 + j);
      PROC4(xv, mv)
      xv = xn; mv = mn;
    }
    PROC4(xv, mv)
  }
  if (blockIdx.x == 0 && threadIdx.x == 0) {  // tail (n not multiple of 4)
    for (long i = n4 * 4; i < n; i++) { PROC(xs[i], ms[i]) }
  }
#undef PROC4
#undef PROC

  // wave shuffle reduce -> block reduce -> PLAIN per-block stores (no atomics)
  for (int off = 32; off > 0; off >>= 1) {
    K += __shfl_down(K, off);
    Cb += __shfl_down(Cb, off);
    T += __shfl_down(T, off);
    T2 += __shfl_down(T2, off);
    Sb += __shfl_down(Sb, off);
  }
  if (lane == 0) { bK[wave] = K; bCb[wave] = Cb; bT[wave] = T; bT2[wave] = T2; bSb[wave] = Sb; }
  __syncthreads();
  if (threadIdx.x == 0) {
    unsigned k = 0, cb = 0; double t = 0.0, t2 = 0.0, sb_ = 0.0;
    for (int w = 0; w < MAIN_NW; w++) {
      k += bK[w]; cb += bCb[w]; t += (double)bT[w]; t2 += (double)bT2[w]; sb_ += (double)bSb[w];
    }
    Kb[blockIdx.x] = k; Cbb[blockIdx.x] = cb;
    Tb[blockIdx.x] = t; T2b[blockIdx.x] = t2; Sbb[blockIdx.x] = sb_;
  }
  if (threadIdx.x < FBINS) {
    int b = threadIdx.x;
    unsigned long long tot = 0ull;
    for (int w = 0; w < MAIN_NW; w++) tot += wh[w][b];
    mh[(long)blockIdx.x * FBINS + b] = tot;   // plain coalesced store
  }
}

// ---------------- stage 4: reduce partials, argmin, output ----------------
__global__ __launch_bounds__(FIN_THREADS)
void k_fin(const double* __restrict__ Tb, const double* __restrict__ T2b,
           const double* __restrict__ Sbb, const unsigned* __restrict__ Kb,
           const unsigned* __restrict__ Cbb,
           const unsigned long long* __restrict__ mh, int nblk,
           float* __restrict__ out) {
  __shared__ double lT[16], lT2[16], lSb[16];
  __shared__ unsigned long long lK[16], lCb[16];
  __shared__ unsigned long long pc[32][FBINS], pq[32][FBINS];  // 16 KiB
  __shared__ double gT, gT2, gSb;
  __shared__ unsigned long long gK, gCb;

  int t = threadIdx.x;
  int wave = t >> 6, lane = t & 63;

  // ---- scalar totals ----
  double T = 0.0, T2 = 0.0, Sb = 0.0;
  unsigned long long K = 0, Cb = 0;
  for (int i = t; i < nblk; i += FIN_THREADS) {
    T += Tb[i]; T2 += T2b[i]; Sb += Sbb[i];
    K += Kb[i]; Cb += Cbb[i];
  }
  for (int off = 32; off > 0; off >>= 1) {
    T += __shfl_down(T, off); T2 += __shfl_down(T2, off); Sb += __shfl_down(Sb, off);
    K += __shfl_down(K, off); Cb += __shfl_down(Cb, off);
  }
  if (lane == 0) { lT[wave] = T; lT2[wave] = T2; lSb[wave] = Sb; lK[wave] = K; lCb[wave] = Cb; }

  // ---- hist totals: thread -> (chunk = t>>5, bin = t&31), chunks stride blocks
  {
    int chunk = t >> 5, bin = t & 31;
    if (chunk < 32) {
      unsigned long long hc = 0, hq = 0;
      for (int i = chunk; i < nblk; i += 32) {
        unsigned long long v = mh[(long)i * FBINS + bin];
        hc += v >> 42; hq += v & ((1ull << 42) - 1ull);
      }
      pc[chunk][bin] = hc; pq[chunk][bin] = hq;
    }
  }
  __syncthreads();

  if (t == 0) {
    double a = 0, b = 0, c = 0; unsigned long long k = 0, cb = 0;
    for (int w = 0; w < 16; w++) { a += lT[w]; b += lT2[w]; c += lSb[w]; k += lK[w]; cb += lCb[w]; }
    gT = a; gT2 = b; gSb = c; gK = k; gCb = cb;
  }
  __syncthreads();

  if (t < 64) {  // wave 0: bins in lanes 0..31, lanes 32..63 ride along
    bool valid = lane < FBINS;
    unsigned long long c = 0, q = 0;
    if (valid) for (int w = 0; w < 32; w++) { c += pc[w][lane]; q += pq[w][lane]; }
    // inclusive scan over 32 bins (full-wave shuffles; upper lanes junk)
    for (int off = 1; off < FBINS; off <<= 1) {
      unsigned long long cc = __shfl_up(c, off);
      unsigned long long qq = __shfl_up(q, off);
      if (lane >= off && valid) { c += cc; q += qq; }
    }
    double kd = (double)gK;
    double T_ = gT, T2_ = gT2;
    double Ccand = 0.0, Scand = 0.0, f = 1.0e300;
    if (valid) {
      Ccand = (double)gCb + (double)c;
      Scand = gSb + ((double)q * 9.5367431640625e-07 - 16.0 * (double)c);
      if (Ccand >= 1.0 && Ccand < kd) {
        double d2 = T_ - Scand;
        f = T2_ - Scand * Scand / Ccand - d2 * d2 / (kd - Ccand);
      } else {
        f = 1.0e300;
      }
      if (lane == 0) {  // extra candidate: split exactly at t_lo (empty prefix)
        double C0 = (double)gCb, S0 = gSb;
        if (C0 >= 1.0 && C0 < kd) {
          double d2 = T_ - S0;
          double f0 = T2_ - S0 * S0 / C0 - d2 * d2 / (kd - C0);
          if (f0 < f) { f = f0; Ccand = C0; Scand = S0; }
        }
      }
    }
    for (int off = 32; off > 0; off >>= 1) {
      double of = __shfl_down(f, off);
      double oS = __shfl_down(Scand, off);
      double oC = __shfl_down(Ccand, off);
      if (of < f) { f = of; Scand = oS; Ccand = oC; }
    }
    if (lane == 0) {
      double result = 0.0;
      if (gK >= 2ull && f < 1.0e300 && Ccand >= 1.0) {
        double var_tot = (T2_ - T_ * T_ / kd) / kd;
        double reg = f / var_tot / kd;
        result = Scand / Ccand + 0.5 * reg;
      }
      out[0] = (float)result;
    }
  }
}

extern "C" void kernel_launch(void* const* d_in, const int* in_sizes, int n_in,
                              void* d_out, int out_size, void* d_ws, size_t ws_size,
                              hipStream_t stream) {
  const float* x = (const float*)d_in[0];
  const int* m = (const int*)d_in[1];
  long n = (long)in_sizes[0];
  long n4 = n >> 2;

  // choose block counts to fit ws_size (deterministic per capture)
  int mb = 512, sb = 32;
  size_t need;
  for (;;) {
    need = 64 + (size_t)mb * (3 * sizeof(double) + 2 * sizeof(unsigned))
         + (size_t)mb * FBINS * 8 + (size_t)sb * SBINS * 8 + 64;
    if (need <= ws_size || (mb <= 64 && sb <= 8)) break;
    if (mb > 64) mb >>= 1;
    else sb >>= 1;
  }

  char* p = (char*)d_ws;
  float* t_lo = (float*)p;
  double* Tb = (double*)(p + 64);
  double* T2b = Tb + mb;
  double* Sbb = T2b + mb;
  unsigned long long* mh = (unsigned long long*)(Sbb + mb);
  unsigned* Kb = (unsigned*)(mh + (size_t)mb * FBINS);
  unsigned* Cbb = Kb + mb;
  unsigned long long* sh =
      (unsigned long long*)(((uintptr_t)(Cbb + mb) + 7) & ~(uintptr_t)7);

  k_sample<<<sb, SAMP_THREADS, 0, stream>>>((const float4*)x, (const int4*)m, n4, sh, sb);
  k_pick<<<1, PICK_THREADS, 0, stream>>>(sh, sb, t_lo);
  k_main<<<mb, MAIN_THREADS, 0, stream>>>((const float4*)x, (const int4*)m, n4,
                                          x, m, n, t_lo, Tb, T2b, Sbb, Kb, Cbb, mh, mb);
  k_fin<<<1, FIN_THREADS, 0, stream>>>(Tb, T2b, Sbb, Kb, Cbb, mh, mb, (float*)d_out);
}